// Round 4
// baseline (81.318 us; speedup 1.0000x reference)
//
#include <hip/hip_runtime.h>

#define K_TERMS 24

// 1/k! table (fp32)
#define INVF_INIT { \
  1.0f, 1.0f, 0.5f, 1.6666666666666666e-01f, 4.1666666666666664e-02f, \
  8.3333333333333332e-03f, 1.3888888888888889e-03f, 1.9841269841269841e-04f, \
  2.4801587301587302e-05f, 2.7557319223985893e-06f, 2.7557319223985888e-07f, \
  2.5052108385441720e-08f, 2.0876756987868098e-09f, 1.6059043836821613e-10f, \
  1.1470745597729725e-11f, 7.6471637318198164e-13f, 4.7794773323873852e-14f, \
  2.8114572543455206e-15f, 1.5619206968586225e-16f, 8.2206352466243295e-18f, \
  4.1103176233121648e-19f, 1.9572941063391263e-20f, 8.8967913924505741e-22f, \
  3.8681701706306835e-23f }

typedef __attribute__((ext_vector_type(4))) float floatx4;
typedef __attribute__((ext_vector_type(8))) short short8;

__device__ __forceinline__ unsigned f2bf_rn(float f) {
  union { float f; unsigned u; } v; v.f = f;
  return (v.u + 0x7FFFu + ((v.u >> 16) & 1u)) >> 16;  // RNE, low 16 valid
}
__device__ __forceinline__ unsigned pk_bf(float lo, float hi) {
  return (f2bf_rn(lo) & 0xFFFFu) | (f2bf_rn(hi) << 16);
}

union S8 { short8 s; unsigned u[4]; };

// ---------------- Kernel 1: t = tanh(img @ W^T + b), barrier-free MFMA ----
// NT GEMM, fragments loaded DIRECTLY from global (k-contiguous rows), bf16
// convert in-register. No LDS, no __syncthreads, depth-4 load pipeline.
// Grid (16 e-tiles, 16 b-tiles) x 256 threads; each wave one 16x16 C tile.
__global__ __launch_bounds__(256) void gemm_tanh_direct(
    const float* __restrict__ img, const float* __restrict__ W,
    const float* __restrict__ bias, float* __restrict__ tdst, int tstride) {
  const int tid = threadIdx.x;
  const int bx = blockIdx.x;       // e-tile (32 wide)
  const int by = blockIdx.y;       // b-tile (32 tall)
  const int wv = tid >> 6, lane = tid & 63;
  const int frow = lane & 15;      // fragment row (m for A, n for B)
  const int kg = lane >> 4;        // k-group 0..3 (8 elems each)
  const int brow = by * 32 + (wv >> 1) * 16 + frow;  // img row
  const int erow = bx * 32 + (wv & 1) * 16 + frow;   // W row

  const float* ap = img + (size_t)brow * 512 + kg * 8;
  const float* wp = W   + (size_t)erow * 512 + kg * 8;

  floatx4 acc = {0.f, 0.f, 0.f, 0.f};
  float4 a0[4], a1[4], w0[4], w1[4];
#pragma unroll
  for (int s = 0; s < 4; ++s) {
    a0[s] = *(const float4*)(ap + s * 32);
    a1[s] = *(const float4*)(ap + s * 32 + 4);
    w0[s] = *(const float4*)(wp + s * 32);
    w1[s] = *(const float4*)(wp + s * 32 + 4);
  }
#pragma unroll
  for (int ks = 0; ks < 16; ++ks) {
    const int sl = ks & 3;
    S8 af, wf;
    af.u[0] = pk_bf(a0[sl].x, a0[sl].y);
    af.u[1] = pk_bf(a0[sl].z, a0[sl].w);
    af.u[2] = pk_bf(a1[sl].x, a1[sl].y);
    af.u[3] = pk_bf(a1[sl].z, a1[sl].w);
    wf.u[0] = pk_bf(w0[sl].x, w0[sl].y);
    wf.u[1] = pk_bf(w0[sl].z, w0[sl].w);
    wf.u[2] = pk_bf(w1[sl].x, w1[sl].y);
    wf.u[3] = pk_bf(w1[sl].z, w1[sl].w);
    acc = __builtin_amdgcn_mfma_f32_16x16x32_bf16(af.s, wf.s, acc, 0, 0, 0);
    if (ks < 12) {  // prefetch step ks+4 into the slot just consumed
      a0[sl] = *(const float4*)(ap + (ks + 4) * 32);
      a1[sl] = *(const float4*)(ap + (ks + 4) * 32 + 4);
      w0[sl] = *(const float4*)(wp + (ks + 4) * 32);
      w1[sl] = *(const float4*)(wp + (ks + 4) * 32 + 4);
    }
  }

  // C/D layout: col = lane&15, row = (lane>>4)*4 + reg  [verified R3]
  const int ecol = bx * 32 + (wv & 1) * 16 + frow;
  const float bv = bias[ecol];
  const int bbase = by * 32 + (wv >> 1) * 16 + kg * 4;
#pragma unroll
  for (int i = 0; i < 4; ++i) {
    tdst[(size_t)(bbase + i) * tstride + ecol] = tanhf(acc[i] + bv);
  }
}

// ---------------- Kernel 2: moment-space co-attention (2 rows/block) ------
__global__ __launch_bounds__(512) void coattn_moments(
    const float* __restrict__ img, const float* __restrict__ audio,
    const float* __restrict__ tsrc, int tstride, float* __restrict__ out) {
  const int tid = threadIdx.x;
  const int b0 = blockIdx.x * 2;

  __shared__ float aL[2][512];    // audio rows
  __shared__ float tL[2][512];    // tanh rows (from kernel 1)
  __shared__ float cwL[2][512];   // a_j / colsum_j
  __shared__ float rwL[2][512];   // t_i / rowsum_i
  __shared__ float gT[2][K_TERMS], gA[2][K_TERMS];
  __shared__ float gS[2][K_TERMS], gR[2][K_TERMS];

  constexpr float INVF[K_TERMS] = INVF_INIT;

  // ---- phase 0: concat copies + stage audio and t ----
#pragma unroll
  for (int s = tid; s < 1024; s += 512) {
    const int r = s >> 9, i = s & 511;
    const float iv = img[(size_t)(b0 + r) * 512 + i];
    const float av = audio[(size_t)(b0 + r) * 512 + i];
    out[(size_t)(b0 + r) * 2048 + i] = iv;
    out[(size_t)(b0 + r) * 2048 + 512 + i] = av;
    aL[r][i] = av;
    tL[r][i] = tsrc[(size_t)(b0 + r) * tstride + i];
  }
  __syncthreads();

  const int wave = tid >> 6, lane = tid & 63;

  // ---- phase 2A: raw moments T_k = sum t^k, A_k = sum a^k (waves 0-3) ----
  if (wave < 4) {
    const int r = wave >> 1, typ = wave & 1;  // typ0: T (tL), typ1: A (aL)
    const float* src = typ ? aL[r] : tL[r];
    float part[K_TERMS];
#pragma unroll
    for (int k = 0; k < K_TERMS; ++k) part[k] = 0.f;
#pragma unroll
    for (int u = 0; u < 8; ++u) {
      const float x = src[lane + 64 * u];
      float p = x;
      part[1] += p;
#pragma unroll
      for (int k = 2; k < K_TERMS; ++k) { p *= x; part[k] += p; }
    }
#pragma unroll
    for (int m = 1; m < 64; m <<= 1) {
#pragma unroll
      for (int k = 1; k < K_TERMS; ++k) part[k] += __shfl_xor(part[k], m, 64);
    }
    if (lane == 0) {
      float* g = typ ? gA[r] : gT[r];
      g[0] = 512.0f;
#pragma unroll
      for (int k = 1; k < K_TERMS; ++k) g[k] = part[k] * INVF[k];
    }
  }
  __syncthreads();

  // ---- phase 2B: colsum/rowsum via Horner -> cw, rw ----
  {
    const int grp = tid >> 7, e0 = tid & 127;
    const int r = grp >> 1, kind = grp & 1;  // kind0: cw (x=a,g=gT); kind1: rw (x=t,g=gA)
    float g[K_TERMS];
    const float* gsrc = kind ? gA[r] : gT[r];
#pragma unroll
    for (int k = 0; k < K_TERMS; ++k) g[k] = gsrc[k];
    const float* xs = kind ? tL[r] : aL[r];
    float* dst = kind ? rwL[r] : cwL[r];
#pragma unroll
    for (int u = 0; u < 4; ++u) {
      const int e = e0 + 128 * u;
      const float x = xs[e];
      float s = g[K_TERMS - 1];
#pragma unroll
      for (int k = K_TERMS - 2; k >= 0; --k) s = fmaf(s, x, g[k]);
      dst[e] = x / s;
    }
  }
  __syncthreads();

  // ---- phase 2C: weighted moments S_k = sum cw*a^k, R_k = sum rw*t^k ----
  if (wave < 4) {
    const int r = wave >> 1, typ = wave & 1;  // typ0: S, typ1: R
    const float* xs = typ ? tL[r] : aL[r];
    const float* ws = typ ? rwL[r] : cwL[r];
    float part[K_TERMS];
#pragma unroll
    for (int k = 0; k < K_TERMS; ++k) part[k] = 0.f;
#pragma unroll
    for (int u = 0; u < 8; ++u) {
      const int i = lane + 64 * u;
      const float x = xs[i];
      float p = ws[i];
      part[0] += p;
#pragma unroll
      for (int k = 1; k < K_TERMS; ++k) { p *= x; part[k] += p; }
    }
#pragma unroll
    for (int m = 1; m < 64; m <<= 1) {
#pragma unroll
      for (int k = 0; k < K_TERMS; ++k) part[k] += __shfl_xor(part[k], m, 64);
    }
    if (lane == 0) {
      float* g = typ ? gR[r] : gS[r];
#pragma unroll
      for (int k = 0; k < K_TERMS; ++k) g[k] = part[k] * INVF[k];
    }
  }
  __syncthreads();

  // ---- phase 2D: outputs C_img (Horner in t, gS) / C_audio (Horner in a, gR)
  {
    const int grp = tid >> 7, e0 = tid & 127;
    const int r = grp >> 1, kind = grp & 1;  // kind0: C_img; kind1: C_audio
    float g[K_TERMS];
    const float* gsrc = kind ? gR[r] : gS[r];
#pragma unroll
    for (int k = 0; k < K_TERMS; ++k) g[k] = gsrc[k];
    const float* xs = kind ? aL[r] : tL[r];
    float* op = out + (size_t)(b0 + r) * 2048 + 1024 + kind * 512;
#pragma unroll
    for (int u = 0; u < 4; ++u) {
      const int e = e0 + 128 * u;
      const float x = xs[e];
      float s = g[K_TERMS - 1];
#pragma unroll
      for (int k = K_TERMS - 2; k >= 0; --k) s = fmaf(s, x, g[k]);
      op[e] = s;
    }
  }
}

extern "C" void kernel_launch(void* const* d_in, const int* in_sizes, int n_in,
                              void* d_out, int out_size, void* d_ws, size_t ws_size,
                              hipStream_t stream) {
  const float* img   = (const float*)d_in[0];
  const float* audio = (const float*)d_in[1];
  const float* W     = (const float*)d_in[2];
  const float* bias  = (const float*)d_in[3];
  float* out = (float*)d_out;

  float* tdst;
  int tstride;
  if (ws_size >= (size_t)(512 * 512 * 4)) {
    tdst = (float*)d_ws;
    tstride = 512;
  } else {
    // fallback: park t in out[:,1024:1536]; K2 reads it in phase 0 before
    // phase 2D overwrites that slice with C_img.
    tdst = out + 1024;
    tstride = 2048;
  }

  hipLaunchKernelGGL(gemm_tanh_direct, dim3(16, 16), dim3(256), 0, stream,
                     img, W, bias, tdst, tstride);
  hipLaunchKernelGGL(coattn_moments, dim3(256), dim3(512), 0, stream,
                     img, audio, tdst, tstride, out);
}

// Round 5
// 76.242 us; speedup vs baseline: 1.0666x; 1.0666x over previous
//
#include <hip/hip_runtime.h>

// R5 = R3 verbatim (best measured: 76.3 us). Session conclusion: measured
// time is dominated by the harness reset floor (~70-75 us: 268 MB ws
// re-poison at 82% achievable HBM + input restores + graph gaps); these two
// kernels contribute ~5 us. R2/R3/R4 structural variants all land 76-81 us
// (noise). Locking in the best-measured variant.

#define K_TERMS 24

// 1/k! table (fp32)
#define INVF_INIT { \
  1.0f, 1.0f, 0.5f, 1.6666666666666666e-01f, 4.1666666666666664e-02f, \
  8.3333333333333332e-03f, 1.3888888888888889e-03f, 1.9841269841269841e-04f, \
  2.4801587301587302e-05f, 2.7557319223985893e-06f, 2.7557319223985888e-07f, \
  2.5052108385441720e-08f, 2.0876756987868098e-09f, 1.6059043836821613e-10f, \
  1.1470745597729725e-11f, 7.6471637318198164e-13f, 4.7794773323873852e-14f, \
  2.8114572543455206e-15f, 1.5619206968586225e-16f, 8.2206352466243295e-18f, \
  4.1103176233121648e-19f, 1.9572941063391263e-20f, 8.8967913924505741e-22f, \
  3.8681701706306835e-23f }

typedef __attribute__((ext_vector_type(4))) float floatx4;
typedef __attribute__((ext_vector_type(8))) short short8;

__device__ __forceinline__ unsigned short f2bf_rn(float f) {
  union { float f; unsigned u; } v; v.f = f;
  const unsigned r = v.u + 0x7FFFu + ((v.u >> 16) & 1u);
  return (unsigned short)(r >> 16);
}

// ---------------- Kernel 1: t = tanh(img @ W^T + b) via bf16 MFMA ---------
// NT GEMM: both img[b][k] and W[e][k] are k-contiguous -> no transpose.
// Grid (16 e-tiles, 16 b-tiles), 256 threads, 32x32 tile, 1 MFMA quad/wave.
__global__ __launch_bounds__(256) void gemm_tanh_mfma(
    const float* __restrict__ img, const float* __restrict__ W,
    const float* __restrict__ bias, float* __restrict__ tdst, int tstride) {
  // row stride 40 shorts = 80 B: 16B-aligned for b128, bank-friendly.
  __shared__ unsigned short Abf[32][40];
  __shared__ unsigned short Wbf[32][40];
  const int tid = threadIdx.x;
  const int bx = blockIdx.x;       // e-tile
  const int by = blockIdx.y;       // b-tile
  const int r  = tid >> 3;         // staging row 0..31
  const int c4 = (tid & 7) * 4;    // staging col 0,4,...,28
  const int lane = tid & 63;
  const int wv = tid >> 6;         // wave 0..3
  const int bm = (wv >> 1) * 16;   // C quadrant row base
  const int en = (wv & 1) * 16;    // C quadrant col base
  const int frow = lane & 15;      // fragment m / n
  const int kg = lane >> 4;        // k-group 0..3 (8 elems each)

  floatx4 acc = {0.f, 0.f, 0.f, 0.f};
  const float* aprow = img + (size_t)(by * 32 + r) * 512;
  const float* wprow = W   + (size_t)(bx * 32 + r) * 512;

  for (int k0 = 0; k0 < 512; k0 += 32) {
    const float4 av = *(const float4*)(aprow + k0 + c4);
    const float4 wl = *(const float4*)(wprow + k0 + c4);
    __syncthreads();  // previous iteration's fragment reads complete
    ushort4 ab, wb;
    ab.x = f2bf_rn(av.x); ab.y = f2bf_rn(av.y);
    ab.z = f2bf_rn(av.z); ab.w = f2bf_rn(av.w);
    wb.x = f2bf_rn(wl.x); wb.y = f2bf_rn(wl.y);
    wb.z = f2bf_rn(wl.z); wb.w = f2bf_rn(wl.w);
    *(ushort4*)&Abf[r][c4] = ab;
    *(ushort4*)&Wbf[r][c4] = wb;
    __syncthreads();  // staging visible
    const short8 afrag = *(const short8*)&Abf[bm + frow][kg * 8];
    const short8 wfrag = *(const short8*)&Wbf[en + frow][kg * 8];
    acc = __builtin_amdgcn_mfma_f32_16x16x32_bf16(afrag, wfrag, acc, 0, 0, 0);
  }

  // C/D layout: col = lane&15, row = (lane>>4)*4 + reg  [measured m89/m91]
  const int e = bx * 32 + en + frow;
  const float bv = bias[e];
  const int b_base = by * 32 + bm + kg * 4;
#pragma unroll
  for (int i = 0; i < 4; ++i) {
    tdst[(size_t)(b_base + i) * tstride + e] = tanhf(acc[i] + bv);
  }
}

// ---------------- Kernel 2: moment-space co-attention (2 rows/block) ------
__global__ __launch_bounds__(512) void coattn_moments(
    const float* __restrict__ img, const float* __restrict__ audio,
    const float* __restrict__ tsrc, int tstride, float* __restrict__ out) {
  const int tid = threadIdx.x;
  const int b0 = blockIdx.x * 2;

  __shared__ float aL[2][512];    // audio rows
  __shared__ float tL[2][512];    // tanh rows (from kernel 1)
  __shared__ float cwL[2][512];   // a_j / colsum_j
  __shared__ float rwL[2][512];   // t_i / rowsum_i
  __shared__ float gT[2][K_TERMS], gA[2][K_TERMS];
  __shared__ float gS[2][K_TERMS], gR[2][K_TERMS];

  constexpr float INVF[K_TERMS] = INVF_INIT;

  // ---- phase 0: concat copies + stage audio and t ----
#pragma unroll
  for (int s = tid; s < 1024; s += 512) {
    const int r = s >> 9, i = s & 511;
    const float iv = img[(size_t)(b0 + r) * 512 + i];
    const float av = audio[(size_t)(b0 + r) * 512 + i];
    out[(size_t)(b0 + r) * 2048 + i] = iv;
    out[(size_t)(b0 + r) * 2048 + 512 + i] = av;
    aL[r][i] = av;
    tL[r][i] = tsrc[(size_t)(b0 + r) * tstride + i];
  }
  __syncthreads();

  const int wave = tid >> 6, lane = tid & 63;

  // ---- phase 2A: raw moments T_k = sum t^k, A_k = sum a^k (waves 0-3) ----
  if (wave < 4) {
    const int r = wave >> 1, typ = wave & 1;  // typ0: T (tL), typ1: A (aL)
    const float* src = typ ? aL[r] : tL[r];
    float part[K_TERMS];
#pragma unroll
    for (int k = 0; k < K_TERMS; ++k) part[k] = 0.f;
#pragma unroll
    for (int u = 0; u < 8; ++u) {
      const float x = src[lane + 64 * u];
      float p = x;
      part[1] += p;
#pragma unroll
      for (int k = 2; k < K_TERMS; ++k) { p *= x; part[k] += p; }
    }
#pragma unroll
    for (int m = 1; m < 64; m <<= 1) {
#pragma unroll
      for (int k = 1; k < K_TERMS; ++k) part[k] += __shfl_xor(part[k], m, 64);
    }
    if (lane == 0) {
      float* g = typ ? gA[r] : gT[r];
      g[0] = 512.0f;
#pragma unroll
      for (int k = 1; k < K_TERMS; ++k) g[k] = part[k] * INVF[k];
    }
  }
  __syncthreads();

  // ---- phase 2B: colsum/rowsum via Horner -> cw, rw ----
  {
    const int grp = tid >> 7, e0 = tid & 127;
    const int r = grp >> 1, kind = grp & 1;  // kind0: cw (x=a,g=gT); kind1: rw (x=t,g=gA)
    float g[K_TERMS];
    const float* gsrc = kind ? gA[r] : gT[r];
#pragma unroll
    for (int k = 0; k < K_TERMS; ++k) g[k] = gsrc[k];
    const float* xs = kind ? tL[r] : aL[r];
    float* dst = kind ? rwL[r] : cwL[r];
#pragma unroll
    for (int u = 0; u < 4; ++u) {
      const int e = e0 + 128 * u;
      const float x = xs[e];
      float s = g[K_TERMS - 1];
#pragma unroll
      for (int k = K_TERMS - 2; k >= 0; --k) s = fmaf(s, x, g[k]);
      dst[e] = x / s;
    }
  }
  __syncthreads();

  // ---- phase 2C: weighted moments S_k = sum cw*a^k, R_k = sum rw*t^k ----
  if (wave < 4) {
    const int r = wave >> 1, typ = wave & 1;  // typ0: S, typ1: R
    const float* xs = typ ? tL[r] : aL[r];
    const float* ws = typ ? rwL[r] : cwL[r];
    float part[K_TERMS];
#pragma unroll
    for (int k = 0; k < K_TERMS; ++k) part[k] = 0.f;
#pragma unroll
    for (int u = 0; u < 8; ++u) {
      const int i = lane + 64 * u;
      const float x = xs[i];
      float p = ws[i];
      part[0] += p;
#pragma unroll
      for (int k = 1; k < K_TERMS; ++k) { p *= x; part[k] += p; }
    }
#pragma unroll
    for (int m = 1; m < 64; m <<= 1) {
#pragma unroll
      for (int k = 0; k < K_TERMS; ++k) part[k] += __shfl_xor(part[k], m, 64);
    }
    if (lane == 0) {
      float* g = typ ? gR[r] : gS[r];
#pragma unroll
      for (int k = 0; k < K_TERMS; ++k) g[k] = part[k] * INVF[k];
    }
  }
  __syncthreads();

  // ---- phase 2D: outputs C_img (Horner in t, gS) / C_audio (Horner in a, gR)
  {
    const int grp = tid >> 7, e0 = tid & 127;
    const int r = grp >> 1, kind = grp & 1;  // kind0: C_img; kind1: C_audio
    float g[K_TERMS];
    const float* gsrc = kind ? gR[r] : gS[r];
#pragma unroll
    for (int k = 0; k < K_TERMS; ++k) g[k] = gsrc[k];
    const float* xs = kind ? aL[r] : tL[r];
    float* op = out + (size_t)(b0 + r) * 2048 + 1024 + kind * 512;
#pragma unroll
    for (int u = 0; u < 4; ++u) {
      const int e = e0 + 128 * u;
      const float x = xs[e];
      float s = g[K_TERMS - 1];
#pragma unroll
      for (int k = K_TERMS - 2; k >= 0; --k) s = fmaf(s, x, g[k]);
      op[e] = s;
    }
  }
}

extern "C" void kernel_launch(void* const* d_in, const int* in_sizes, int n_in,
                              void* d_out, int out_size, void* d_ws, size_t ws_size,
                              hipStream_t stream) {
  const float* img   = (const float*)d_in[0];
  const float* audio = (const float*)d_in[1];
  const float* W     = (const float*)d_in[2];
  const float* bias  = (const float*)d_in[3];
  float* out = (float*)d_out;

  float* tdst;
  int tstride;
  if (ws_size >= (size_t)(512 * 512 * 4)) {
    tdst = (float*)d_ws;
    tstride = 512;
  } else {
    // fallback: park t in the out[:,1024:1536] slice; K2 reads it in phase 0
    // (before phase 2D overwrites that slice with C_img).
    tdst = out + 1024;
    tstride = 2048;
  }

  hipLaunchKernelGGL(gemm_tanh_mfma, dim3(16, 16), dim3(256), 0, stream,
                     img, W, bias, tdst, tstride);
  hipLaunchKernelGGL(coattn_moments, dim3(256), dim3(512), 0, stream,
                     img, audio, tdst, tstride, out);
}